// Round 2
// baseline (841.851 us; speedup 1.0000x reference)
//
#include <hip/hip_runtime.h>
#include <math.h>

#define LATENT   1024
#define WORD     64
#define NB_WORD  8192
#define BATCH    2048
#define NROWS    (BATCH * LATENT / WORD)   // 32768
#define NELEM    (BATCH * LATENT)          // 2097152

#define BM       32                        // rows per block
#define BN       128                       // codewords per tile
#define PADW     68                        // padded LDS row stride (floats): bank-start stride 4
#define NTILES   (NB_WORD / BN)            // 64

// ---------------- kernel 1: e2[m] = sum_k emb[m][k]^2 ----------------
__global__ __launch_bounds__(256) void vq_e2_kernel(
    const float* __restrict__ emb, float* __restrict__ e2) {
    int m = blockIdx.x * 256 + threadIdx.x;
    if (m >= NB_WORD) return;
    const float4* ep = reinterpret_cast<const float4*>(emb + (size_t)m * WORD);
    float s0 = 0.f, s1 = 0.f, s2 = 0.f, s3 = 0.f;
#pragma unroll
    for (int i = 0; i < 16; ++i) {
        float4 v = ep[i];
        s0 = fmaf(v.x, v.x, s0);
        s1 = fmaf(v.y, v.y, s1);
        s2 = fmaf(v.z, v.z, s2);
        s3 = fmaf(v.w, v.w, s3);
    }
    e2[m] = (s0 + s1) + (s2 + s3);
}

// ---------------- kernel 2: tiled register-blocked argmin -------------
// Block: 32 rows x all 8192 codewords (tiles of 128). Lane (r,c) owns rows
// {r, r+16} x codewords {c+16s, s=0..7} per tile. All operands via LDS.
__global__ __launch_bounds__(256, 3) void vq_argmin_kernel(
    const float* __restrict__ z, const float* __restrict__ emb,
    const float* __restrict__ e2, unsigned long long* __restrict__ best) {

    __shared__ float lz[BM * PADW];    // 8704 B
    __shared__ float le[BN * PADW];    // 34816 B
    __shared__ float le2[BN];          // 512 B

    const int tid = threadIdx.x;
    const int c   = tid & 15;
    const int r   = tid >> 4;
    const int rowbase = blockIdx.x * BM;

    // ---- stage z tile (once) ----
#pragma unroll
    for (int j = 0; j < 2; ++j) {
        int idx = tid + 256 * j;            // float4 index within tile
        int row = idx >> 4, kk = idx & 15;
        float4 v = reinterpret_cast<const float4*>(z)[(size_t)(rowbase + row) * 16 + kk];
        *reinterpret_cast<float4*>(&lz[row * PADW + kk * 4]) = v;
    }
    __syncthreads();

    // ---- per-lane z2 for its two rows ----
    float z2v[2];
#pragma unroll
    for (int i = 0; i < 2; ++i) {
        const float* zr = &lz[(r + 16 * i) * PADW];
        float a0 = 0.f, a1 = 0.f, a2 = 0.f, a3 = 0.f;
#pragma unroll
        for (int g = 0; g < 16; ++g) {
            float4 v = *reinterpret_cast<const float4*>(&zr[4 * g]);
            a0 = fmaf(v.x, v.x, a0);
            a1 = fmaf(v.y, v.y, a1);
            a2 = fmaf(v.z, v.z, a2);
            a3 = fmaf(v.w, v.w, a3);
        }
        z2v[i] = (a0 + a1) + (a2 + a3);
    }

    // ---- prefetch regs for e tile ----
    float4 ereg[8];
    float  e2reg = 0.f;
    {
#pragma unroll
        for (int j = 0; j < 8; ++j)
            ereg[j] = reinterpret_cast<const float4*>(emb)[(size_t)tid + 256 * j];
        if (tid < BN) e2reg = e2[tid];
    }

    float bestd0 = INFINITY, bestd1 = INFINITY;
    int   bestm0 = 0,        bestm1 = 0;

    for (int t = 0; t < NTILES; ++t) {
        __syncthreads();   // previous tile's readers done
        // write staged regs -> LDS (padded rows)
#pragma unroll
        for (int j = 0; j < 8; ++j) {
            int idx = tid + 256 * j;
            int cw = idx >> 4, kk = idx & 15;
            *reinterpret_cast<float4*>(&le[cw * PADW + kk * 4]) = ereg[j];
        }
        if (tid < BN) le2[tid] = e2reg;
        // issue next tile's global loads (latency hidden under compute)
        if (t + 1 < NTILES) {
#pragma unroll
            for (int j = 0; j < 8; ++j)
                ereg[j] = reinterpret_cast<const float4*>(emb)
                              [(size_t)(t + 1) * (BN * 16) + tid + 256 * j];
            if (tid < BN) e2reg = e2[(t + 1) * BN + tid];
        }
        __syncthreads();

        // ---- compute 2x8 accumulator micro-tile over K=64 ----
        float acc0[8] = {0.f, 0.f, 0.f, 0.f, 0.f, 0.f, 0.f, 0.f};
        float acc1[8] = {0.f, 0.f, 0.f, 0.f, 0.f, 0.f, 0.f, 0.f};
#pragma unroll 4
        for (int g = 0; g < 16; ++g) {
            float4 za = *reinterpret_cast<const float4*>(&lz[r * PADW + 4 * g]);
            float4 zb = *reinterpret_cast<const float4*>(&lz[(r + 16) * PADW + 4 * g]);
#pragma unroll
            for (int s = 0; s < 8; ++s) {
                float4 ev = *reinterpret_cast<const float4*>(&le[(c + 16 * s) * PADW + 4 * g]);
                acc0[s] = fmaf(za.x, ev.x, acc0[s]);
                acc0[s] = fmaf(za.y, ev.y, acc0[s]);
                acc0[s] = fmaf(za.z, ev.z, acc0[s]);
                acc0[s] = fmaf(za.w, ev.w, acc0[s]);
                acc1[s] = fmaf(zb.x, ev.x, acc1[s]);
                acc1[s] = fmaf(zb.y, ev.y, acc1[s]);
                acc1[s] = fmaf(zb.z, ev.z, acc1[s]);
                acc1[s] = fmaf(zb.w, ev.w, acc1[s]);
            }
        }

        // ---- fold argmin ----
#pragma unroll
        for (int s = 0; s < 8; ++s) {
            int   m   = t * BN + c + 16 * s;
            float e2m = le2[c + 16 * s];
            float d0  = fmaf(-2.0f, acc0[s], z2v[0] + e2m);
            float d1  = fmaf(-2.0f, acc1[s], z2v[1] + e2m);
            if (d0 < bestd0) { bestd0 = d0; bestm0 = m; }
            if (d1 < bestd1) { bestd1 = d1; bestm1 = m; }
        }
    }

    // ---- cross-lane (16 c-lanes share a row) packed-u64 min reduce ----
#pragma unroll
    for (int i = 0; i < 2; ++i) {
        float bd = i ? bestd1 : bestd0;
        int   bm = i ? bestm1 : bestm0;
        unsigned int db = __float_as_uint(bd);
        db = (db & 0x80000000u) ? ~db : (db | 0x80000000u);
        unsigned long long key =
            ((unsigned long long)db << 32) | (unsigned int)bm;
#pragma unroll
        for (int off = 1; off < 16; off <<= 1) {
            unsigned long long other = __shfl_xor(key, off);
            key = (other < key) ? other : key;
        }
        if (c == 0) best[rowbase + r + 16 * i] = key;
    }
}

// ---------------- kernel 3: gather + straight-through output + loss ---
__global__ __launch_bounds__(256) void vq_out_kernel(
    const float* __restrict__ z, const float* __restrict__ emb,
    const unsigned long long* __restrict__ best,
    float* __restrict__ out, float* __restrict__ lsum) {
    const int base = (blockIdx.x * 256 + threadIdx.x) * 8;   // 8 elems/thread
    const int row  = base >> 6;                              // 8 | 64, row fixed
    const int m    = (int)(best[row] & 0xFFFFFFFFull);

    const float4* zp = reinterpret_cast<const float4*>(z + base);
    const float4* qp = reinterpret_cast<const float4*>(emb + (size_t)m * WORD + (base & 63));
    float4* op = reinterpret_cast<float4*>(out + base);

    float s = 0.f;
#pragma unroll
    for (int i = 0; i < 2; ++i) {
        float4 zv = zp[i];
        float4 qv = qp[i];
        float dx = qv.x - zv.x, dy = qv.y - zv.y, dz = qv.z - zv.z, dw = qv.w - zv.w;
        float4 ov;
        ov.x = zv.x + dx; ov.y = zv.y + dy; ov.z = zv.z + dz; ov.w = zv.w + dw;
        op[i] = ov;
        s += dx*dx + dy*dy + dz*dz + dw*dw;
    }

    // wave reduce
#pragma unroll
    for (int off = 32; off > 0; off >>= 1) s += __shfl_down(s, off);
    __shared__ float wsum[4];
    int lane = threadIdx.x & 63, wid = threadIdx.x >> 6;
    if (lane == 0) wsum[wid] = s;
    __syncthreads();
    if (threadIdx.x == 0)
        atomicAdd(lsum, (wsum[0] + wsum[1]) + (wsum[2] + wsum[3]));
}

// ---------------- kernel 4: finalize loss -----------------------------
__global__ void vq_loss_kernel(const float* __restrict__ lsum,
                               float* __restrict__ loss_out) {
    float mean = lsum[0] * (1.0f / (float)NELEM);   // /2^21 exact
    loss_out[0] = mean + 2.5f * mean;
}

extern "C" void kernel_launch(void* const* d_in, const int* in_sizes, int n_in,
                              void* d_out, int out_size, void* d_ws, size_t ws_size,
                              hipStream_t stream) {
    const float* z   = (const float*)d_in[0];   // z_mean (2048,1024)
    // d_in[1] = z_log_var, unused by the reference
    const float* emb = (const float*)d_in[2];   // (8192,64)
    float* out = (float*)d_out;                 // [z_q_st flat (2097152), loss]

    // ws layout: e2 (8192 f32) | best (32768 u64) | lsum (1 f32)
    float* e2 = (float*)d_ws;
    unsigned long long* best =
        (unsigned long long*)((char*)d_ws + NB_WORD * sizeof(float));
    float* lsum = (float*)((char*)best + NROWS * sizeof(unsigned long long));

    hipMemsetAsync(lsum, 0, sizeof(float), stream);

    vq_e2_kernel<<<NB_WORD / 256, 256, 0, stream>>>(emb, e2);
    vq_argmin_kernel<<<NROWS / BM, 256, 0, stream>>>(z, emb, e2, best);
    vq_out_kernel<<<NELEM / (256 * 8), 256, 0, stream>>>(z, emb, best, out, lsum);
    vq_loss_kernel<<<1, 1, 0, stream>>>(lsum, out + NELEM);
}